// Round 11
// baseline (365.865 us; speedup 1.0000x reference)
//
#include <hip/hip_runtime.h>
#include <cstddef>
#include <cmath>

// Problem constants
#define NROWS 16384   // 32*512
#define DIM   512
#define KC    2048

// d_out layout (float32 element offsets)
#define Q_OFF    0ul          // 8,388,608 elems (pre-GEMM: Ah/Al planes; then divpart2[2048][2048]+entpart[2048]; finally quantized)
#define LOSS_OFF 8388608ul    // 33,554,432 elems (reused as sim scratch)
#define NN_OFF   41943040ul   // 16,384 elems
#define CB_OFF   41959424ul   // 1,048,576 elems (pre-GEMM: Bh/Bl planes; later part2; finally codebook copy)
#define CNT_OFF  43008000ul   // 2,048 elems

#define ENT_OFF  4194304ul    // entpart[2048] lives in Q region after divpart2 (dead until tail; fin2 runs before tail)

#define FLAG_CAP 4096
#define FLAG_TAU 3e-5f        // 3-term split: observed argmax errors ~1e-6; 3e-5 passed r1-r3

// ws layout (32-bit slots)
#define WS_LOSS   0
#define WS_CNT    4       // 2048 ints
#define WS_NFLAG  3076
#define WS_FLAGS  3080    // 3*4096 ints
#define WS_DIVLOG 15376   // 8 floats

typedef __attribute__((ext_vector_type(8))) short short8;
typedef __attribute__((ext_vector_type(4))) float f32x4;

// ----------------------------------------------------------- bf16 split -----
__device__ __forceinline__ short hi1(float f) {
    return (short)(__float_as_uint(f) >> 16);
}
__device__ __forceinline__ short lo1(float f) {
    unsigned int u = __float_as_uint(f);
    float l = f - __uint_as_float(u & 0xffff0000u);
    return (short)(__float_as_uint(l) >> 16);
}
__device__ __forceinline__ short8 hi8(float4 a, float4 b) {
    short8 r;
    r[0]=hi1(a.x); r[1]=hi1(a.y); r[2]=hi1(a.z); r[3]=hi1(a.w);
    r[4]=hi1(b.x); r[5]=hi1(b.y); r[6]=hi1(b.z); r[7]=hi1(b.w);
    return r;
}
__device__ __forceinline__ short8 lo8(float4 a, float4 b) {
    short8 r;
    r[0]=lo1(a.x); r[1]=lo1(a.y); r[2]=lo1(a.z); r[3]=lo1(a.w);
    r[4]=lo1(b.x); r[5]=lo1(b.y); r[6]=lo1(b.z); r[7]=lo1(b.w);
    return r;
}

// -------------------------------------------------------------- pre-conv ----
__global__ __launch_bounds__(256) void convsplit(const float* __restrict__ x,
                                                 const float* __restrict__ cb,
                                                 ushort* __restrict__ ah,
                                                 ushort* __restrict__ al,
                                                 ushort* __restrict__ bh,
                                                 ushort* __restrict__ bl,
                                                 int* __restrict__ ws) {
    if (blockIdx.x == 0) {
        for (int j = threadIdx.x + WS_CNT; j < WS_CNT + 2048; j += 256) ws[j] = 0;
        if (threadIdx.x == 0) ws[WS_NFLAG] = 0;
    }
    size_t i = (size_t)blockIdx.x * 256 + threadIdx.x;   // 8 floats per thread
    const float* src; ushort* dh; ushort* dl; size_t off;
    if (i < 1048576ul) {                // A: 16384*512/8 threads
        src = x;  dh = ah; dl = al; off = i * 8;
    } else {                            // B: 2048*512/8 threads
        src = cb; dh = bh; dl = bl; off = (i - 1048576ul) * 8;
    }
    float4 a = *(const float4*)(src + off);
    float4 b = *(const float4*)(src + off + 4);
    *(short8*)(dh + off) = hi8(a, b);
    *(short8*)(dl + off) = lo8(a, b);
}

// ---------------------------------------------------------------- GEMM ------
// Verified r9: 105 us, MfmaUtil 42%, bank-conflicts 0, VALUBusy 16% — at the
// m97-structure ceiling (~980 TF). Next lever here would be the 8-phase 256^2
// schedule; unchanged this round.
__global__ __launch_bounds__(256, 3) void gemm_mfma(const ushort* __restrict__ Ah,
                                                    const ushort* __restrict__ Al,
                                                    const ushort* __restrict__ Bh,
                                                    const ushort* __restrict__ Bl,
                                                    float* __restrict__ C) {
    __shared__ ushort smem[16384];   // 32 KB, single-buffered (m97 structure)
    const int t    = threadIdx.x;
    const int n0   = blockIdx.x * 128;
    const int m0   = blockIdx.y * 128;
    const int lane = t & 63, quad = lane >> 4, lr = lane & 15;
    const int w = t >> 6, wm = w >> 1, wn = w & 1;

    f32x4 acc[4][4] = {};

    const int srow = w * 32 + (lane >> 2);
    const int gc   = (((lane & 3) ^ ((lane >> 3) & 3)) << 3);

    const ushort* gAh0 = Ah + (size_t)(m0 + srow) * DIM + gc;
    const ushort* gAh1 = gAh0 + 16 * DIM;
    const ushort* gAl0 = Al + (size_t)(m0 + srow) * DIM + gc;
    const ushort* gAl1 = gAl0 + 16 * DIM;
    const ushort* gBh0 = Bh + (size_t)(n0 + srow) * DIM + gc;
    const ushort* gBh1 = gBh0 + 16 * DIM;
    const ushort* gBl0 = Bl + (size_t)(n0 + srow) * DIM + gc;
    const ushort* gBl1 = gBl0 + 16 * DIM;

    ushort* lAh = smem +     0 + w * 1024;
    ushort* lAl = smem +  4096 + w * 1024;
    ushort* lBh = smem +  8192 + w * 1024;
    ushort* lBl = smem + 12288 + w * 1024;

    const int swz = ((quad ^ ((lr >> 1) & 3)) << 3);
    const ushort* ra = smem +        (wm * 64 + lr) * 32 + swz;
    const ushort* rb = smem + 8192 + (wn * 64 + lr) * 32 + swz;

    #pragma unroll 1
    for (int kk = 0; kk < 16; ++kk) {
        const int k0 = kk * 32;
        #define GLD16(G, L)                                                         \
            __builtin_amdgcn_global_load_lds(                                       \
                (const __attribute__((address_space(1))) unsigned int*)(G),         \
                (__attribute__((address_space(3))) unsigned int*)(L), 16, 0, 0)
        GLD16(gAh0 + k0, lAh);
        GLD16(gAh1 + k0, lAh + 512);
        GLD16(gAl0 + k0, lAl);
        GLD16(gAl1 + k0, lAl + 512);
        GLD16(gBh0 + k0, lBh);
        GLD16(gBh1 + k0, lBh + 512);
        GLD16(gBl0 + k0, lBl);
        GLD16(gBl1 + k0, lBl + 512);
        #undef GLD16
        __syncthreads();

        short8 ah[4], al[4], bx[4];
        #pragma unroll
        for (int mt = 0; mt < 4; ++mt) ah[mt] = *(const short8*)(ra + mt * 512);
        #pragma unroll
        for (int nt = 0; nt < 4; ++nt) bx[nt] = *(const short8*)(rb + nt * 512);
        #pragma unroll
        for (int mt = 0; mt < 4; ++mt)
            #pragma unroll
            for (int nt = 0; nt < 4; ++nt)
                acc[mt][nt] = __builtin_amdgcn_mfma_f32_16x16x32_bf16(ah[mt], bx[nt], acc[mt][nt], 0, 0, 0);
        #pragma unroll
        for (int mt = 0; mt < 4; ++mt) al[mt] = *(const short8*)(ra + 4096 + mt * 512);
        #pragma unroll
        for (int mt = 0; mt < 4; ++mt)
            #pragma unroll
            for (int nt = 0; nt < 4; ++nt)
                acc[mt][nt] = __builtin_amdgcn_mfma_f32_16x16x32_bf16(al[mt], bx[nt], acc[mt][nt], 0, 0, 0);
        #pragma unroll
        for (int nt = 0; nt < 4; ++nt) bx[nt] = *(const short8*)(rb + 4096 + nt * 512);
        #pragma unroll
        for (int mt = 0; mt < 4; ++mt)
            #pragma unroll
            for (int nt = 0; nt < 4; ++nt)
                acc[mt][nt] = __builtin_amdgcn_mfma_f32_16x16x32_bf16(ah[mt], bx[nt], acc[mt][nt], 0, 0, 0);
        __syncthreads();
    }

    #pragma unroll
    for (int mt = 0; mt < 4; ++mt) {
        #pragma unroll
        for (int nt = 0; nt < 4; ++nt) {
            const int r0 = m0 + wm * 64 + mt * 16 + quad * 4;
            const int c0 = n0 + wn * 64 + nt * 16 + lr;
            #pragma unroll
            for (int j = 0; j < 4; ++j)
                C[(size_t)(r0 + j) * KC + c0] = acc[mt][nt][j];
        }
    }
}

// ------------------------------------------------------------ block reduce --
__device__ __forceinline__ float block_reduce_sum(float v, volatile float* sf,
                                                  int lane, int w) {
    #pragma unroll
    for (int off = 32; off; off >>= 1) v += __shfl_xor(v, off, 64);
    if (lane == 0) sf[w] = v;
    __syncthreads();
    v = sf[0] + sf[1] + sf[2] + sf[3];
    __syncthreads();
    return v;
}

// ---------------------------------------------------------------- row pass --
// r10 change: 2048 blocks x 8 rows (2 rows/wave) instead of 1024 x 16 —
// 32 waves/CU (max occupancy) to hide the serial load->scan->shuffle chain.
// Per-row math unchanged (bit-identical); only row->block mapping changed.
__global__ __launch_bounds__(256, 4) void rowpass(const float* __restrict__ sim,
                                                  float* __restrict__ nn,
                                                  float* __restrict__ divpart2,  // [2048][2048]
                                                  int*   __restrict__ counts,
                                                  float* __restrict__ entpart,   // [2048] (Q region)
                                                  int*   __restrict__ nflag,
                                                  int*   __restrict__ flags) {
    __shared__ float divp[KC];
    __shared__ float sent[4];
    const int t = threadIdx.x, lane = t & 63, w = t >> 6;
    const int b = blockIdx.x;
    const int row0 = b * 8 + w * 2;
    const int col0 = lane << 2;

    float4 dacc[8] = {};
    float ent_acc = 0.f;
    const float* base = sim + (size_t)row0 * KC + col0;

    #pragma unroll 1
    for (int rr = 0; rr < 2; ++rr) {
        float4 cur[8];
        const float* rp = base + (size_t)rr * KC;
        #pragma unroll
        for (int j = 0; j < 8; ++j) cur[j] = *(const float4*)(rp + 256 * j);

        // ---- top-2 (value, index), first-occurrence tie rule ----
        float bv = -3.0e38f, rv = -3.0e38f;
        int   bi = 0x7fffffff, ri = 0x7fffffff;
        #pragma unroll
        for (int j = 0; j < 8; ++j) {
            #pragma unroll
            for (int c = 0; c < 4; ++c) {
                float v = (&cur[j].x)[c];
                int   i = col0 + c + 256 * j;
                if (v > bv || (v == bv && i < bi)) { rv = bv; ri = bi; bv = v; bi = i; }
                else if (v > rv || (v == rv && i < ri)) { rv = v; ri = i; }
            }
        }
        #pragma unroll
        for (int off = 32; off; off >>= 1) {
            float obv = __shfl_xor(bv, off, 64);
            int   obi = __shfl_xor(bi, off, 64);
            float orv = __shfl_xor(rv, off, 64);
            int   ori = __shfl_xor(ri, off, 64);
            bool ob = (obv > bv) || (obv == bv && obi < bi);
            float c1v = ob ? bv : obv;  int c1i = ob ? bi : obi;
            float c2v = ob ? orv : rv;  int c2i = ob ? ori : ri;
            bv = ob ? obv : bv;  bi = ob ? obi : bi;
            bool rb = (c1v > c2v) || (c1v == c2v && c1i < c2i);
            rv = rb ? c1v : c2v;  ri = rb ? c1i : c2i;
        }
        const float m = bv;

        // ---- softmax stats: Z = sum e, S = sum e*(s-m) ----
        float Z = 0.f, S = 0.f;
        #pragma unroll
        for (int j = 0; j < 8; ++j) {
            #pragma unroll
            for (int c = 0; c < 4; ++c) {
                float d = (&cur[j].x)[c] - m;
                float e = expf(d);
                Z += e; S += e * d;
                (&cur[j].x)[c] = e;
            }
        }
        #pragma unroll
        for (int off = 32; off; off >>= 1) {
            Z += __shfl_xor(Z, off, 64);
            S += __shfl_xor(S, off, 64);
        }
        const float inv = 1.0f / Z;
        #pragma unroll
        for (int j = 0; j < 8; ++j) {
            dacc[j].x += cur[j].x * inv; dacc[j].y += cur[j].y * inv;
            dacc[j].z += cur[j].z * inv; dacc[j].w += cur[j].w * inv;
        }

        if (lane == 0) {
            // sum p*log2(p+1e-8) = log2e*(S/Z) - log2(Z) + 2048*1e-8*log2e
            ent_acc += 1.4426950408889634f * (S * inv) - log2f(Z) + 2.9546393e-5f;
            atomicAdd(&counts[bi], 1);
            nn[row0 + rr] = (float)bi;
            if (bv - rv < FLAG_TAU) {
                int e = atomicAdd(nflag, 1);
                if (e < FLAG_CAP) {
                    flags[3*e] = row0 + rr; flags[3*e+1] = bi; flags[3*e+2] = ri;
                }
            }
        }
    }

    if (lane == 0) sent[w] = ent_acc;
    // deterministic cross-wave diversity combine
    for (int ww = 0; ww < 4; ++ww) {
        if (w == ww) {
            #pragma unroll
            for (int j = 0; j < 8; ++j) {
                float4* p = (float4*)&divp[col0 + 256 * j];
                if (ww == 0) *p = dacc[j];
                else {
                    float4 v = *p;
                    v.x += dacc[j].x; v.y += dacc[j].y;
                    v.z += dacc[j].z; v.w += dacc[j].w;
                    *p = v;
                }
            }
        }
        __syncthreads();
    }
    float4* dst = (float4*)(divpart2 + (size_t)b * KC);
    dst[t]       = *(float4*)&divp[t * 4];
    dst[t + 256] = *(float4*)&divp[t * 4 + 1024];
    if (t == 0) entpart[b] = sent[0] + sent[1] + sent[2] + sent[3];
}

// --------------------------------------------- fixup + fin1a (one launch) ---
// blocks [0,128): column partial sums of divpart2[2048] -> part2[128][2048]
// blocks [128,256): exact fp32 re-check of flagged near-tie rows
__global__ __launch_bounds__(256) void fixfin(const float* __restrict__ divpart2,
                                              float* __restrict__ part2,
                                              const float* __restrict__ A,
                                              const float* __restrict__ B,
                                              float* __restrict__ nn,
                                              int*   __restrict__ counts,
                                              const int* __restrict__ flags,
                                              const int* __restrict__ nflagp) {
    const int t = threadIdx.x;
    if (blockIdx.x < 128) {
        const int b = blockIdx.x;
        const float* dp = divpart2 + (size_t)b * 16 * KC;
        #pragma unroll
        for (int j = 0; j < 8; ++j) {
            int c = t + 256 * j;
            float s = 0.f;
            #pragma unroll
            for (int r = 0; r < 16; ++r) s += dp[(size_t)r * KC + c];
            part2[(size_t)b * KC + c] = s;
        }
    } else {
        __shared__ float sf[4];
        int nf = *nflagp; if (nf > FLAG_CAP) nf = FLAG_CAP;
        const int lane = t & 63, w = t >> 6;
        for (int e = blockIdx.x - 128; e < nf; e += 128) {
            const int row = flags[3*e], i1 = flags[3*e+1], i2 = flags[3*e+2];
            const float* ar = A + (size_t)row * DIM;
            const float* b1 = B + (size_t)i1 * DIM;
            const float* b2 = B + (size_t)i2 * DIM;
            float d1 = ar[t] * b1[t] + ar[t + 256] * b1[t + 256];
            float d2 = ar[t] * b2[t] + ar[t + 256] * b2[t + 256];
            d1 = block_reduce_sum(d1, sf, lane, w);
            d2 = block_reduce_sum(d2, sf, lane, w);
            if (t == 0 && (d2 > d1 || (d2 == d1 && i2 < i1))) {
                nn[row] = (float)i2;
                atomicSub(&counts[i1], 1);
                atomicAdd(&counts[i2], 1);
            }
            __syncthreads();
        }
    }
}

// ------------------------------------------------------------- finalize -----
__global__ __launch_bounds__(256) void fin1b(const float* __restrict__ part2,
                                             float* __restrict__ divlog8) {
    __shared__ float sf[4];
    const int t = threadIdx.x, lane = t & 63, w = t >> 6;
    const int c = blockIdx.x * 256 + t;
    float s = 0.f;
    for (int r = 0; r < 128; ++r) s += part2[(size_t)r * KC + c];
    float d = s * (1.0f / 16384.0f);
    float v = d * log2f(d + 1e-8f);
    float S = block_reduce_sum(v, sf, lane, w);
    if (t == 0) divlog8[blockIdx.x] = S;
}

__global__ __launch_bounds__(256) void fin2(const float* __restrict__ entpart,
                                            const float* __restrict__ divlog8,
                                            float* __restrict__ lossp) {
    __shared__ float sf[4];
    const int t = threadIdx.x, lane = t & 63, w = t >> 6;
    float se = 0.f;
    #pragma unroll
    for (int k = 0; k < 8; ++k) se += entpart[t + 256 * k];
    float Se = block_reduce_sum(se, sf, lane, w);
    float Sd = block_reduce_sum((t < 8) ? divlog8[t] : 0.f, sf, lane, w);
    if (t == 0)
        lossp[0] = (float)(-(double)Se / 16384.0 + (double)Sd);
}

// ------------------------------------------------------- quantize+epilogue --
// r10: loss broadcast now 4 coalesced float4 stores per thread (8192 blocks).
__global__ __launch_bounds__(256) void tail(const float* __restrict__ x,
                                            const float* __restrict__ cb,
                                            const float* __restrict__ oldc,
                                            const int*   __restrict__ counts,
                                            const float* __restrict__ lossp,
                                            const int*   __restrict__ train,
                                            const float* __restrict__ nn,
                                            float* __restrict__ out) {
    const int bb = blockIdx.x;
    const int t  = threadIdx.x;
    if (bb < 4096) {
        const int lane = t & 63;
        const int row  = (bb << 2) + (t >> 6);
        const int idx  = (int)nn[row];
        const float* c  = cb + (size_t)idx * DIM;
        const float* xr = x  + (size_t)row * DIM;

        float4 q0 = *(const float4*)(c + lane * 8);
        float4 q1 = *(const float4*)(c + lane * 8 + 4);

        float s = q0.x+q0.y+q0.z+q0.w + q1.x+q1.y+q1.z+q1.w;
        #pragma unroll
        for (int off = 32; off; off >>= 1) s += __shfl_xor(s, off, 64);
        const float mean = s * (1.0f / 512.0f);
        q0.x -= mean; q0.y -= mean; q0.z -= mean; q0.w -= mean;
        q1.x -= mean; q1.y -= mean; q1.z -= mean; q1.w -= mean;

        float ss = q0.x*q0.x+q0.y*q0.y+q0.z*q0.z+q0.w*q0.w
                 + q1.x*q1.x+q1.y*q1.y+q1.z*q1.z+q1.w*q1.w;
        #pragma unroll
        for (int off = 32; off; off >>= 1) ss += __shfl_xor(ss, off, 64);
        const float inv = 1.0f / sqrtf(ss);

        float4 x0 = *(const float4*)(xr + lane * 8);
        float4 x1 = *(const float4*)(xr + lane * 8 + 4);
        float4 o0, o1;
        o0.x = x0.x + (q0.x*inv - x0.x); o0.y = x0.y + (q0.y*inv - x0.y);
        o0.z = x0.z + (q0.z*inv - x0.z); o0.w = x0.w + (q0.w*inv - x0.w);
        o1.x = x1.x + (q1.x*inv - x1.x); o1.y = x1.y + (q1.y*inv - x1.y);
        o1.z = x1.z + (q1.z*inv - x1.z); o1.w = x1.w + (q1.w*inv - x1.w);
        *(float4*)(out + (size_t)row * DIM + lane * 8)     = o0;
        *(float4*)(out + (size_t)row * DIM + lane * 8 + 4) = o1;
    } else {
        const int bb2 = bb - 4096;
        if (bb2 < 8192) {
            // loss broadcast: 4 coalesced float4 stores per thread
            const float l = lossp[0];
            const float4 v = make_float4(l, l, l, l);
            float4* lo = (float4*)(out + LOSS_OFF);
            size_t base4 = (size_t)bb2 * 1024 + t;
            lo[base4]       = v;
            lo[base4 + 256] = v;
            lo[base4 + 512] = v;
            lo[base4 + 768] = v;
        } else if (bb2 < 8192 + 1024) {
            size_t j = (size_t)(bb2 - 8192) * 256 + t;
            ((float4*)(out + CB_OFF))[j] = ((const float4*)cb)[j];
        } else {
            int k = (bb2 - 9216) * 256 + t;   // 8 blocks -> 2048
            float nc = train[0] ? 0.99f * oldc[k] + 0.01f * (float)counts[k]
                                : oldc[k];
            out[CNT_OFF + k] = nc;
        }
    }
}

// ------------------------------------------------------------------ launch --
extern "C" void kernel_launch(void* const* d_in, const int* in_sizes, int n_in,
                              void* d_out, int out_size, void* d_ws, size_t ws_size,
                              hipStream_t stream) {
    const float* x     = (const float*)d_in[0];
    const float* cb    = (const float*)d_in[1];
    const float* oldc  = (const float*)d_in[2];
    const int*   train = (const int*)d_in[3];
    float* out = (float*)d_out;

    float* sim      = out + LOSS_OFF;
    float* divpart2 = out + Q_OFF;                 // [2048][2048]
    float* entpart  = out + Q_OFF + ENT_OFF;       // [2048], after divpart2
    float* part2    = out + CB_OFF;
    float* nn       = out + NN_OFF;

    ushort* Ah = (ushort*)(out + Q_OFF);
    ushort* Al = Ah + 8388608ul;
    ushort* Bh = (ushort*)(out + CB_OFF);
    ushort* Bl = Bh + 1048576ul;

    float* lossp   = (float*)d_ws + WS_LOSS;
    int*   counts  = (int*)d_ws   + WS_CNT;
    int*   nflag   = (int*)d_ws   + WS_NFLAG;
    int*   flags   = (int*)d_ws   + WS_FLAGS;
    float* divlog8 = (float*)d_ws + WS_DIVLOG;

    convsplit<<<4608, 256, 0, stream>>>(x, cb, Ah, Al, Bh, Bl, (int*)d_ws);
    gemm_mfma<<<dim3(KC / 128, NROWS / 128), 256, 0, stream>>>(Ah, Al, Bh, Bl, sim);
    rowpass<<<2048, 256, 0, stream>>>(sim, nn, divpart2, counts, entpart, nflag, flags);
    fixfin<<<256, 256, 0, stream>>>(divpart2, part2, x, cb, nn, counts, flags, nflag);
    fin1b<<<8, 256, 0, stream>>>(part2, divlog8);
    fin2<<<1, 256, 0, stream>>>(entpart, divlog8, lossp);
    tail<<<4096 + 9224, 256, 0, stream>>>(x, cb, oldc, counts, lossp, train, nn, out);
}

// Round 12
// 354.067 us; speedup vs baseline: 1.0333x; 1.0333x over previous
//
#include <hip/hip_runtime.h>
#include <cstddef>
#include <cmath>

// Problem constants
#define NROWS 16384   // 32*512
#define DIM   512
#define KC    2048

// d_out layout (float32 element offsets)
#define Q_OFF    0ul          // 8,388,608 elems (pre-GEMM: Ah/Al planes; then divpart2[2048][2048]+entpart[2048]; finally quantized)
#define LOSS_OFF 8388608ul    // 33,554,432 elems (reused as sim scratch)
#define NN_OFF   41943040ul   // 16,384 elems
#define CB_OFF   41959424ul   // 1,048,576 elems (pre-GEMM: Bh/Bl planes; later part2; finally codebook copy)
#define CNT_OFF  43008000ul   // 2,048 elems

#define ENT_OFF  4194304ul    // entpart[2048] lives in Q region after divpart2 (dead until tail; fin2 runs before tail)

#define FLAG_CAP 4096
#define FLAG_TAU 3e-5f        // 3-term split: observed argmax errors ~1e-6; 3e-5 passed r1-r3

// ws layout (32-bit slots)
#define WS_LOSS   0
#define WS_CNT    4       // 2048 ints
#define WS_NFLAG  3076
#define WS_FLAGS  3080    // 3*4096 ints
#define WS_DIVLOG 15376   // 8 floats

typedef __attribute__((ext_vector_type(8))) short short8;
typedef __attribute__((ext_vector_type(4))) float f32x4;

// ----------------------------------------------------------- bf16 split -----
__device__ __forceinline__ short hi1(float f) {
    return (short)(__float_as_uint(f) >> 16);
}
__device__ __forceinline__ short lo1(float f) {
    unsigned int u = __float_as_uint(f);
    float l = f - __uint_as_float(u & 0xffff0000u);
    return (short)(__float_as_uint(l) >> 16);
}
__device__ __forceinline__ short8 hi8(float4 a, float4 b) {
    short8 r;
    r[0]=hi1(a.x); r[1]=hi1(a.y); r[2]=hi1(a.z); r[3]=hi1(a.w);
    r[4]=hi1(b.x); r[5]=hi1(b.y); r[6]=hi1(b.z); r[7]=hi1(b.w);
    return r;
}
__device__ __forceinline__ short8 lo8(float4 a, float4 b) {
    short8 r;
    r[0]=lo1(a.x); r[1]=lo1(a.y); r[2]=lo1(a.z); r[3]=lo1(a.w);
    r[4]=lo1(b.x); r[5]=lo1(b.y); r[6]=lo1(b.z); r[7]=lo1(b.w);
    return r;
}

// -------------------------------------------------------------- pre-conv ----
__global__ __launch_bounds__(256) void convsplit(const float* __restrict__ x,
                                                 const float* __restrict__ cb,
                                                 ushort* __restrict__ ah,
                                                 ushort* __restrict__ al,
                                                 ushort* __restrict__ bh,
                                                 ushort* __restrict__ bl,
                                                 int* __restrict__ ws) {
    if (blockIdx.x == 0) {
        for (int j = threadIdx.x + WS_CNT; j < WS_CNT + 2048; j += 256) ws[j] = 0;
        if (threadIdx.x == 0) ws[WS_NFLAG] = 0;
    }
    size_t i = (size_t)blockIdx.x * 256 + threadIdx.x;   // 8 floats per thread
    const float* src; ushort* dh; ushort* dl; size_t off;
    if (i < 1048576ul) {                // A: 16384*512/8 threads
        src = x;  dh = ah; dl = al; off = i * 8;
    } else {                            // B: 2048*512/8 threads
        src = cb; dh = bh; dl = bl; off = (i - 1048576ul) * 8;
    }
    float4 a = *(const float4*)(src + off);
    float4 b = *(const float4*)(src + off + 4);
    *(short8*)(dh + off) = hi8(a, b);
    *(short8*)(dl + off) = lo8(a, b);
}

// ---------------------------------------------------------------- GEMM ------
// r12: 256x256 tile, BK=32, 512 threads (8 waves 2Mx4N), double-buffered
// 128 KB LDS, 3 phases per K-step (one per term AhBh/AlBh/AhBl), raw
// s_barrier + COUNTED vmcnt (never 0 in the loop) per guide T3/T4, setprio
// around MFMA clusters (T5). Same chunk-XOR swizzle (verified 0 conflicts),
// same per-K-step term order as r9/r11 -> bit-identical accumulation.
//
// Load order per K-step prefetch (FIFO): L1=Ah0 L2=Ah1 L3=Bh0 | L4=Bh1
// L5=Al0 L6=Al1 | L7=Bl0 L8=Bl1.  Steady-state waits: end-ph1 vmcnt(5)
// (retires Al), end-ph2 vmcnt(6) (retires Bl), end-ph3 vmcnt(4) (retires
// next Ah+Bh).  Prologue vmcnt(4); epilogue drains 2 -> 0.
#define P_AH 0
#define P_AL 8192
#define P_BH 16384
#define P_BL 24576
#define BUFS 32768

__global__ __launch_bounds__(512, 2) void gemm_mfma(const ushort* __restrict__ Ah,
                                                    const ushort* __restrict__ Al,
                                                    const ushort* __restrict__ Bh,
                                                    const ushort* __restrict__ Bl,
                                                    float* __restrict__ C) {
    __shared__ ushort smem[65536];   // 128 KB
    const int t    = threadIdx.x;
    const int n0   = blockIdx.x * 256;
    const int m0   = blockIdx.y * 256;
    const int lane = t & 63, quad = lane >> 4, lr = lane & 15;
    const int w = t >> 6, wm = w >> 2, wn = w & 3;
    const int wb = w * 1024;

    f32x4 acc[8][4] = {};

    // staging: wave w covers rows [w*32, w*32+32) of each 256-row panel,
    // as 2 x 1KB global_load_lds per plane. Same swizzle math as r9 (verified).
    const int srow = w * 32 + (lane >> 2);
    const int gc   = (((lane & 3) ^ ((lane >> 3) & 3)) << 3);

    const ushort* gAh0 = Ah + (size_t)(m0 + srow) * DIM + gc;
    const ushort* gAh1 = gAh0 + 16 * DIM;
    const ushort* gAl0 = Al + (size_t)(m0 + srow) * DIM + gc;
    const ushort* gAl1 = gAl0 + 16 * DIM;
    const ushort* gBh0 = Bh + (size_t)(n0 + srow) * DIM + gc;
    const ushort* gBh1 = gBh0 + 16 * DIM;
    const ushort* gBl0 = Bl + (size_t)(n0 + srow) * DIM + gc;
    const ushort* gBl1 = gBl0 + 16 * DIM;

    // read addrs: A frag row = wm*128 + mt*16 + lr; B frag row = wn*64 + nt*16 + lr
    const int swz   = ((quad ^ ((lr >> 1) & 3)) << 3);
    const int raOff = (wm * 128 + lr) * 32 + swz;   // + mt*512 within plane
    const int rbOff = (wn * 64  + lr) * 32 + swz;   // + nt*512 within plane

    #define GLD16(G, LOFF)                                                          \
        __builtin_amdgcn_global_load_lds(                                           \
            (const __attribute__((address_space(1))) unsigned int*)(G),             \
            (__attribute__((address_space(3))) unsigned int*)(smem + (LOFF)), 16, 0, 0)

    // ---- prologue: stage K-step 0 into buf0 (order L1..L8), publish Ah+Bh
    GLD16(gAh0, P_AH + wb);
    GLD16(gAh1, P_AH + wb + 512);
    GLD16(gBh0, P_BH + wb);
    GLD16(gBh1, P_BH + wb + 512);
    GLD16(gAl0, P_AL + wb);
    GLD16(gAl1, P_AL + wb + 512);
    GLD16(gBl0, P_BL + wb);
    GLD16(gBl1, P_BL + wb + 512);
    asm volatile("s_waitcnt vmcnt(4)" ::: "memory");
    __builtin_amdgcn_s_barrier();
    __builtin_amdgcn_sched_barrier(0);

    short8 ah[8], bb[4], al[8], bl[4];

    #pragma unroll 1
    for (int kk = 0; kk < 15; ++kk) {
        const int cb  = (kk & 1) * BUFS;
        const int nb  = cb ^ BUFS;
        const int k0n = (kk + 1) * 32;

        // ---------- phase 1: term Ah x Bh ----------
        #pragma unroll
        for (int mt = 0; mt < 8; ++mt) ah[mt] = *(const short8*)(smem + cb + P_AH + raOff + mt * 512);
        #pragma unroll
        for (int nt = 0; nt < 4; ++nt) bb[nt] = *(const short8*)(smem + cb + P_BH + rbOff + nt * 512);
        GLD16(gAh0 + k0n, nb + P_AH + wb);
        GLD16(gAh1 + k0n, nb + P_AH + wb + 512);
        GLD16(gBh0 + k0n, nb + P_BH + wb);
        asm volatile("s_waitcnt vmcnt(5)" ::: "memory");
        __builtin_amdgcn_s_barrier();
        __builtin_amdgcn_sched_barrier(0);
        __builtin_amdgcn_s_setprio(1);
        #pragma unroll
        for (int mt = 0; mt < 8; ++mt)
            #pragma unroll
            for (int nt = 0; nt < 4; ++nt)
                acc[mt][nt] = __builtin_amdgcn_mfma_f32_16x16x32_bf16(ah[mt], bb[nt], acc[mt][nt], 0, 0, 0);
        __builtin_amdgcn_s_setprio(0);
        __builtin_amdgcn_s_barrier();
        __builtin_amdgcn_sched_barrier(0);

        // ---------- phase 2: term Al x Bh ----------
        #pragma unroll
        for (int mt = 0; mt < 8; ++mt) al[mt] = *(const short8*)(smem + cb + P_AL + raOff + mt * 512);
        GLD16(gBh1 + k0n, nb + P_BH + wb + 512);
        GLD16(gAl0 + k0n, nb + P_AL + wb);
        GLD16(gAl1 + k0n, nb + P_AL + wb + 512);
        asm volatile("s_waitcnt vmcnt(6)" ::: "memory");
        __builtin_amdgcn_s_barrier();
        __builtin_amdgcn_sched_barrier(0);
        __builtin_amdgcn_s_setprio(1);
        #pragma unroll
        for (int mt = 0; mt < 8; ++mt)
            #pragma unroll
            for (int nt = 0; nt < 4; ++nt)
                acc[mt][nt] = __builtin_amdgcn_mfma_f32_16x16x32_bf16(al[mt], bb[nt], acc[mt][nt], 0, 0, 0);
        __builtin_amdgcn_s_setprio(0);
        __builtin_amdgcn_s_barrier();
        __builtin_amdgcn_sched_barrier(0);

        // ---------- phase 3: term Ah x Bl ----------
        #pragma unroll
        for (int nt = 0; nt < 4; ++nt) bl[nt] = *(const short8*)(smem + cb + P_BL + rbOff + nt * 512);
        GLD16(gBl0 + k0n, nb + P_BL + wb);
        GLD16(gBl1 + k0n, nb + P_BL + wb + 512);
        asm volatile("s_waitcnt vmcnt(4)" ::: "memory");
        __builtin_amdgcn_s_barrier();
        __builtin_amdgcn_sched_barrier(0);
        __builtin_amdgcn_s_setprio(1);
        #pragma unroll
        for (int mt = 0; mt < 8; ++mt)
            #pragma unroll
            for (int nt = 0; nt < 4; ++nt)
                acc[mt][nt] = __builtin_amdgcn_mfma_f32_16x16x32_bf16(ah[mt], bl[nt], acc[mt][nt], 0, 0, 0);
        __builtin_amdgcn_s_setprio(0);
        __builtin_amdgcn_s_barrier();
        __builtin_amdgcn_sched_barrier(0);
    }

    // ---- epilogue: K-step 15 (no prefetch; drain 2 -> 0) ----
    {
        const int cb = BUFS;   // (15 & 1) * BUFS
        #pragma unroll
        for (int mt = 0; mt < 8; ++mt) ah[mt] = *(const short8*)(smem + cb + P_AH + raOff + mt * 512);
        #pragma unroll
        for (int nt = 0; nt < 4; ++nt) bb[nt] = *(const short8*)(smem + cb + P_BH + rbOff + nt * 512);
        asm volatile("s_waitcnt vmcnt(2)" ::: "memory");
        __builtin_amdgcn_s_barrier();
        __builtin_amdgcn_sched_barrier(0);
        #pragma unroll
        for (int mt = 0; mt < 8; ++mt)
            #pragma unroll
            for (int nt = 0; nt < 4; ++nt)
                acc[mt][nt] = __builtin_amdgcn_mfma_f32_16x16x32_bf16(ah[mt], bb[nt], acc[mt][nt], 0, 0, 0);
        __builtin_amdgcn_s_barrier();
        __builtin_amdgcn_sched_barrier(0);

        #pragma unroll
        for (int mt = 0; mt < 8; ++mt) al[mt] = *(const short8*)(smem + cb + P_AL + raOff + mt * 512);
        asm volatile("s_waitcnt vmcnt(0)" ::: "memory");
        __builtin_amdgcn_s_barrier();
        __builtin_amdgcn_sched_barrier(0);
        #pragma unroll
        for (int mt = 0; mt < 8; ++mt)
            #pragma unroll
            for (int nt = 0; nt < 4; ++nt)
                acc[mt][nt] = __builtin_amdgcn_mfma_f32_16x16x32_bf16(al[mt], bb[nt], acc[mt][nt], 0, 0, 0);
        __builtin_amdgcn_s_barrier();
        __builtin_amdgcn_sched_barrier(0);

        #pragma unroll
        for (int nt = 0; nt < 4; ++nt) bl[nt] = *(const short8*)(smem + cb + P_BL + rbOff + nt * 512);
        #pragma unroll
        for (int mt = 0; mt < 8; ++mt)
            #pragma unroll
            for (int nt = 0; nt < 4; ++nt)
                acc[mt][nt] = __builtin_amdgcn_mfma_f32_16x16x32_bf16(ah[mt], bl[nt], acc[mt][nt], 0, 0, 0);
    }
    #undef GLD16

    #pragma unroll
    for (int mt = 0; mt < 8; ++mt) {
        #pragma unroll
        for (int nt = 0; nt < 4; ++nt) {
            const int r0 = m0 + wm * 128 + mt * 16 + quad * 4;
            const int c0 = n0 + wn * 64 + nt * 16 + lr;
            #pragma unroll
            for (int j = 0; j < 4; ++j)
                C[(size_t)(r0 + j) * KC + c0] = acc[mt][nt][j];
        }
    }
}

// ------------------------------------------------------------ block reduce --
__device__ __forceinline__ float block_reduce_sum(float v, volatile float* sf,
                                                  int lane, int w) {
    #pragma unroll
    for (int off = 32; off; off >>= 1) v += __shfl_xor(v, off, 64);
    if (lane == 0) sf[w] = v;
    __syncthreads();
    v = sf[0] + sf[1] + sf[2] + sf[3];
    __syncthreads();
    return v;
}

// ---------------------------------------------------------------- row pass --
__global__ __launch_bounds__(256, 4) void rowpass(const float* __restrict__ sim,
                                                  float* __restrict__ nn,
                                                  float* __restrict__ divpart2,  // [2048][2048]
                                                  int*   __restrict__ counts,
                                                  float* __restrict__ entpart,   // [2048] (Q region)
                                                  int*   __restrict__ nflag,
                                                  int*   __restrict__ flags) {
    __shared__ float divp[KC];
    __shared__ float sent[4];
    const int t = threadIdx.x, lane = t & 63, w = t >> 6;
    const int b = blockIdx.x;
    const int row0 = b * 8 + w * 2;
    const int col0 = lane << 2;

    float4 dacc[8] = {};
    float ent_acc = 0.f;
    const float* base = sim + (size_t)row0 * KC + col0;

    #pragma unroll 1
    for (int rr = 0; rr < 2; ++rr) {
        float4 cur[8];
        const float* rp = base + (size_t)rr * KC;
        #pragma unroll
        for (int j = 0; j < 8; ++j) cur[j] = *(const float4*)(rp + 256 * j);

        // ---- top-2 (value, index), first-occurrence tie rule ----
        float bv = -3.0e38f, rv = -3.0e38f;
        int   bi = 0x7fffffff, ri = 0x7fffffff;
        #pragma unroll
        for (int j = 0; j < 8; ++j) {
            #pragma unroll
            for (int c = 0; c < 4; ++c) {
                float v = (&cur[j].x)[c];
                int   i = col0 + c + 256 * j;
                if (v > bv || (v == bv && i < bi)) { rv = bv; ri = bi; bv = v; bi = i; }
                else if (v > rv || (v == rv && i < ri)) { rv = v; ri = i; }
            }
        }
        #pragma unroll
        for (int off = 32; off; off >>= 1) {
            float obv = __shfl_xor(bv, off, 64);
            int   obi = __shfl_xor(bi, off, 64);
            float orv = __shfl_xor(rv, off, 64);
            int   ori = __shfl_xor(ri, off, 64);
            bool ob = (obv > bv) || (obv == bv && obi < bi);
            float c1v = ob ? bv : obv;  int c1i = ob ? bi : obi;
            float c2v = ob ? orv : rv;  int c2i = ob ? ori : ri;
            bv = ob ? obv : bv;  bi = ob ? obi : bi;
            bool rb = (c1v > c2v) || (c1v == c2v && c1i < c2i);
            rv = rb ? c1v : c2v;  ri = rb ? c1i : c2i;
        }
        const float m = bv;

        // ---- softmax stats: Z = sum e, S = sum e*(s-m) ----
        float Z = 0.f, S = 0.f;
        #pragma unroll
        for (int j = 0; j < 8; ++j) {
            #pragma unroll
            for (int c = 0; c < 4; ++c) {
                float d = (&cur[j].x)[c] - m;
                float e = expf(d);
                Z += e; S += e * d;
                (&cur[j].x)[c] = e;
            }
        }
        #pragma unroll
        for (int off = 32; off; off >>= 1) {
            Z += __shfl_xor(Z, off, 64);
            S += __shfl_xor(S, off, 64);
        }
        const float inv = 1.0f / Z;
        #pragma unroll
        for (int j = 0; j < 8; ++j) {
            dacc[j].x += cur[j].x * inv; dacc[j].y += cur[j].y * inv;
            dacc[j].z += cur[j].z * inv; dacc[j].w += cur[j].w * inv;
        }

        if (lane == 0) {
            // sum p*log2(p+1e-8) = log2e*(S/Z) - log2(Z) + 2048*1e-8*log2e
            ent_acc += 1.4426950408889634f * (S * inv) - log2f(Z) + 2.9546393e-5f;
            atomicAdd(&counts[bi], 1);
            nn[row0 + rr] = (float)bi;
            if (bv - rv < FLAG_TAU) {
                int e = atomicAdd(nflag, 1);
                if (e < FLAG_CAP) {
                    flags[3*e] = row0 + rr; flags[3*e+1] = bi; flags[3*e+2] = ri;
                }
            }
        }
    }

    if (lane == 0) sent[w] = ent_acc;
    // deterministic cross-wave diversity combine
    for (int ww = 0; ww < 4; ++ww) {
        if (w == ww) {
            #pragma unroll
            for (int j = 0; j < 8; ++j) {
                float4* p = (float4*)&divp[col0 + 256 * j];
                if (ww == 0) *p = dacc[j];
                else {
                    float4 v = *p;
                    v.x += dacc[j].x; v.y += dacc[j].y;
                    v.z += dacc[j].z; v.w += dacc[j].w;
                    *p = v;
                }
            }
        }
        __syncthreads();
    }
    float4* dst = (float4*)(divpart2 + (size_t)b * KC);
    dst[t]       = *(float4*)&divp[t * 4];
    dst[t + 256] = *(float4*)&divp[t * 4 + 1024];
    if (t == 0) entpart[b] = sent[0] + sent[1] + sent[2] + sent[3];
}

// --------------------------------------------- fixup + fin1a (one launch) ---
__global__ __launch_bounds__(256) void fixfin(const float* __restrict__ divpart2,
                                              float* __restrict__ part2,
                                              const float* __restrict__ A,
                                              const float* __restrict__ B,
                                              float* __restrict__ nn,
                                              int*   __restrict__ counts,
                                              const int* __restrict__ flags,
                                              const int* __restrict__ nflagp) {
    const int t = threadIdx.x;
    if (blockIdx.x < 128) {
        const int b = blockIdx.x;
        const float* dp = divpart2 + (size_t)b * 16 * KC;
        #pragma unroll
        for (int j = 0; j < 8; ++j) {
            int c = t + 256 * j;
            float s = 0.f;
            #pragma unroll
            for (int r = 0; r < 16; ++r) s += dp[(size_t)r * KC + c];
            part2[(size_t)b * KC + c] = s;
        }
    } else {
        __shared__ float sf[4];
        int nf = *nflagp; if (nf > FLAG_CAP) nf = FLAG_CAP;
        const int lane = t & 63, w = t >> 6;
        for (int e = blockIdx.x - 128; e < nf; e += 128) {
            const int row = flags[3*e], i1 = flags[3*e+1], i2 = flags[3*e+2];
            const float* ar = A + (size_t)row * DIM;
            const float* b1 = B + (size_t)i1 * DIM;
            const float* b2 = B + (size_t)i2 * DIM;
            float d1 = ar[t] * b1[t] + ar[t + 256] * b1[t + 256];
            float d2 = ar[t] * b2[t] + ar[t + 256] * b2[t + 256];
            d1 = block_reduce_sum(d1, sf, lane, w);
            d2 = block_reduce_sum(d2, sf, lane, w);
            if (t == 0 && (d2 > d1 || (d2 == d1 && i2 < i1))) {
                nn[row] = (float)i2;
                atomicSub(&counts[i1], 1);
                atomicAdd(&counts[i2], 1);
            }
            __syncthreads();
        }
    }
}

// ------------------------------------------------------------- finalize -----
__global__ __launch_bounds__(256) void fin1b(const float* __restrict__ part2,
                                             float* __restrict__ divlog8) {
    __shared__ float sf[4];
    const int t = threadIdx.x, lane = t & 63, w = t >> 6;
    const int c = blockIdx.x * 256 + t;
    float s = 0.f;
    for (int r = 0; r < 128; ++r) s += part2[(size_t)r * KC + c];
    float d = s * (1.0f / 16384.0f);
    float v = d * log2f(d + 1e-8f);
    float S = block_reduce_sum(v, sf, lane, w);
    if (t == 0) divlog8[blockIdx.x] = S;
}

__global__ __launch_bounds__(256) void fin2(const float* __restrict__ entpart,
                                            const float* __restrict__ divlog8,
                                            float* __restrict__ lossp) {
    __shared__ float sf[4];
    const int t = threadIdx.x, lane = t & 63, w = t >> 6;
    float se = 0.f;
    #pragma unroll
    for (int k = 0; k < 8; ++k) se += entpart[t + 256 * k];
    float Se = block_reduce_sum(se, sf, lane, w);
    float Sd = block_reduce_sum((t < 8) ? divlog8[t] : 0.f, sf, lane, w);
    if (t == 0)
        lossp[0] = (float)(-(double)Se / 16384.0 + (double)Sd);
}

// ------------------------------------------------------- quantize+epilogue --
__global__ __launch_bounds__(256) void tail(const float* __restrict__ x,
                                            const float* __restrict__ cb,
                                            const float* __restrict__ oldc,
                                            const int*   __restrict__ counts,
                                            const float* __restrict__ lossp,
                                            const int*   __restrict__ train,
                                            const float* __restrict__ nn,
                                            float* __restrict__ out) {
    const int bb = blockIdx.x;
    const int t  = threadIdx.x;
    if (bb < 4096) {
        const int lane = t & 63;
        const int row  = (bb << 2) + (t >> 6);
        const int idx  = (int)nn[row];
        const float* c  = cb + (size_t)idx * DIM;
        const float* xr = x  + (size_t)row * DIM;

        float4 q0 = *(const float4*)(c + lane * 8);
        float4 q1 = *(const float4*)(c + lane * 8 + 4);

        float s = q0.x+q0.y+q0.z+q0.w + q1.x+q1.y+q1.z+q1.w;
        #pragma unroll
        for (int off = 32; off; off >>= 1) s += __shfl_xor(s, off, 64);
        const float mean = s * (1.0f / 512.0f);
        q0.x -= mean; q0.y -= mean; q0.z -= mean; q0.w -= mean;
        q1.x -= mean; q1.y -= mean; q1.z -= mean; q1.w -= mean;

        float ss = q0.x*q0.x+q0.y*q0.y+q0.z*q0.z+q0.w*q0.w
                 + q1.x*q1.x+q1.y*q1.y+q1.z*q1.z+q1.w*q1.w;
        #pragma unroll
        for (int off = 32; off; off >>= 1) ss += __shfl_xor(ss, off, 64);
        const float inv = 1.0f / sqrtf(ss);

        float4 x0 = *(const float4*)(xr + lane * 8);
        float4 x1 = *(const float4*)(xr + lane * 8 + 4);
        float4 o0, o1;
        o0.x = x0.x + (q0.x*inv - x0.x); o0.y = x0.y + (q0.y*inv - x0.y);
        o0.z = x0.z + (q0.z*inv - x0.z); o0.w = x0.w + (q0.w*inv - x0.w);
        o1.x = x1.x + (q1.x*inv - x1.x); o1.y = x1.y + (q1.y*inv - x1.y);
        o1.z = x1.z + (q1.z*inv - x1.z); o1.w = x1.w + (q1.w*inv - x1.w);
        *(float4*)(out + (size_t)row * DIM + lane * 8)     = o0;
        *(float4*)(out + (size_t)row * DIM + lane * 8 + 4) = o1;
    } else {
        const int bb2 = bb - 4096;
        if (bb2 < 8192) {
            // loss broadcast: 4 coalesced float4 stores per thread
            const float l = lossp[0];
            const float4 v = make_float4(l, l, l, l);
            float4* lo = (float4*)(out + LOSS_OFF);
            size_t base4 = (size_t)bb2 * 1024 + t;
            lo[base4]       = v;
            lo[base4 + 256] = v;
            lo[base4 + 512] = v;
            lo[base4 + 768] = v;
        } else if (bb2 < 8192 + 1024) {
            size_t j = (size_t)(bb2 - 8192) * 256 + t;
            ((float4*)(out + CB_OFF))[j] = ((const float4*)cb)[j];
        } else {
            int k = (bb2 - 9216) * 256 + t;   // 8 blocks -> 2048
            float nc = train[0] ? 0.99f * oldc[k] + 0.01f * (float)counts[k]
                                : oldc[k];
            out[CNT_OFF + k] = nc;
        }
    }
}

// ------------------------------------------------------------------ launch --
extern "C" void kernel_launch(void* const* d_in, const int* in_sizes, int n_in,
                              void* d_out, int out_size, void* d_ws, size_t ws_size,
                              hipStream_t stream) {
    const float* x     = (const float*)d_in[0];
    const float* cb    = (const float*)d_in[1];
    const float* oldc  = (const float*)d_in[2];
    const int*   train = (const int*)d_in[3];
    float* out = (float*)d_out;

    float* sim      = out + LOSS_OFF;
    float* divpart2 = out + Q_OFF;                 // [2048][2048]
    float* entpart  = out + Q_OFF + ENT_OFF;       // [2048], after divpart2
    float* part2    = out + CB_OFF;
    float* nn       = out + NN_OFF;

    ushort* Ah = (ushort*)(out + Q_OFF);
    ushort* Al = Ah + 8388608ul;
    ushort* Bh = (ushort*)(out + CB_OFF);
    ushort* Bl = Bh + 1048576ul;

    float* lossp   = (float*)d_ws + WS_LOSS;
    int*   counts  = (int*)d_ws   + WS_CNT;
    int*   nflag   = (int*)d_ws   + WS_NFLAG;
    int*   flags   = (int*)d_ws   + WS_FLAGS;
    float* divlog8 = (float*)d_ws + WS_DIVLOG;

    convsplit<<<4608, 256, 0, stream>>>(x, cb, Ah, Al, Bh, Bl, (int*)d_ws);
    gemm_mfma<<<dim3(KC / 256, NROWS / 256), 512, 0, stream>>>(Ah, Al, Bh, Bl, sim);
    rowpass<<<2048, 256, 0, stream>>>(sim, nn, divpart2, counts, entpart, nflag, flags);
    fixfin<<<256, 256, 0, stream>>>(divpart2, part2, x, cb, nn, counts, flags, nflag);
    fin1b<<<8, 256, 0, stream>>>(part2, divlog8);
    fin2<<<1, 256, 0, stream>>>(entpart, divlog8, lossp);
    tail<<<4096 + 9224, 256, 0, stream>>>(x, cb, oldc, counts, lossp, train, nn, out);
}